// Round 1
// baseline (70.653 us; speedup 1.0000x reference)
//
#include <hip/hip_runtime.h>
#include <math.h>

// Hausdorff distance between binary masks on a 96x96 grid, batch 8, mean.
// Exact separable squared-distance transform:
//   min_{q in tgt} dist^2(p,q) = min_r [ (p_i - r)^2 + g[r][p_j] ],
//   g[r][j] = (nearest set column in row r to j)^2   (two integer sweeps).
// All integer-exact until the final sqrt(d2)/96.

#define HH 96
#define WW 96
#define HW (HH * WW)          // 9216
#define GSTR 97               // +1 pad: phase-2 reads g[r*97+j] conflict-free
#define NSLICE 8
#define CELLS_PER_SLICE (HW / NSLICE)   // 1152
#define BLK 256
#define SENT 1000             // 1D sentinel distance; SENT^2 = 1e6 >> max real 18050

__device__ __forceinline__ int imin(int a, int b) { return a < b ? a : b; }

__global__ __launch_bounds__(BLK) void haus_partial(
    const float* __restrict__ predict, const float* __restrict__ target,
    float* __restrict__ ws_partial)
{
    __shared__ unsigned char tgt[HH * GSTR];
    __shared__ int g[HH * GSTR];
    __shared__ float redbuf[BLK / 64];

    const int bid   = blockIdx.x;
    const int n     = bid >> 4;        // sample
    const int dir   = (bid >> 3) & 1;  // 0: src=A\B tgt=B ; 1: src=B\A tgt=A
    const int slice = bid & 7;
    const int tid   = threadIdx.x;

    const float* pbase = predict + n * HW;
    const float* tbase = target  + n * HW;
    const float* tgsrc = (dir == 0) ? tbase : pbase;

    // ---- load target-set mask into LDS (coalesced) ----
    for (int p = tid; p < HW; p += BLK) {
        int r = p / WW, c = p - r * WW;
        tgt[r * GSTR + c] = (tgsrc[p] > 0.5f) ? 1 : 0;
    }
    __syncthreads();

    // ---- per-row 1D squared distance to nearest set column (2 sweeps) ----
    if (tid < HH) {
        const int r = tid;
        const unsigned char* trow = tgt + r * GSTR;
        int* grow = g + r * GSTR;
        int d = SENT;
        for (int j = 0; j < WW; ++j) {
            d = trow[j] ? 0 : imin(d + 1, SENT);
            grow[j] = d;
        }
        d = SENT;
        for (int j = WW - 1; j >= 0; --j) {
            d = trow[j] ? 0 : imin(d + 1, SENT);
            int dist = imin(d, grow[j]);
            grow[j] = dist * dist;   // <= 1e6 sentinel; real values <= 9025
        }
    }
    __syncthreads();

    // ---- phase 2: per-cell min over rows, max over src cells ----
    float local = 0.0f;
    const int cell0 = slice * CELLS_PER_SLICE;
    for (int cell = cell0 + tid; cell < cell0 + CELLS_PER_SLICE; cell += BLK) {
        int i = cell / WW, j = cell - i * WW;
        bool a = pbase[cell] > 0.5f;
        bool b = tbase[cell] > 0.5f;
        bool src = (dir == 0) ? (a && !b) : (b && !a);

        int m = 0x7FFFFFFF;
        #pragma unroll 32
        for (int r = 0; r < HH; ++r) {
            int di = i - r;
            int v = g[r * GSTR + j] + di * di;
            m = imin(m, v);
        }
        if (src) {
            // m >= SENT^2 means target set empty -> reference yields BIG=1e9
            float dmin = (m < SENT * SENT) ? sqrtf((float)m) * (1.0f / 96.0f)
                                           : 1e9f;
            local = fmaxf(local, dmin);
        }
    }

    // ---- block max-reduce ----
    for (int off = 32; off; off >>= 1)
        local = fmaxf(local, __shfl_xor(local, off, 64));
    if ((tid & 63) == 0) redbuf[tid >> 6] = local;
    __syncthreads();
    if (tid == 0) {
        float m = redbuf[0];
        for (int w = 1; w < BLK / 64; ++w) m = fmaxf(m, redbuf[w]);
        ws_partial[bid] = m;
    }
}

__global__ __launch_bounds__(128) void haus_final(
    const float* __restrict__ ws_partial, float* __restrict__ out)
{
    __shared__ float buf[128];
    __shared__ float hs[8];
    int tid = threadIdx.x;
    buf[tid] = ws_partial[tid];
    __syncthreads();
    if (tid < 8) {
        // haus[n] = max(distA, distB) = max over all 16 partials of sample n
        float m = 0.0f;
        for (int k = 0; k < 16; ++k) m = fmaxf(m, buf[tid * 16 + k]);
        hs[tid] = m;
    }
    __syncthreads();
    if (tid == 0) {
        float s = 0.0f;
        for (int k = 0; k < 8; ++k) s += hs[k];
        out[0] = s * 0.125f;
    }
}

extern "C" void kernel_launch(void* const* d_in, const int* in_sizes, int n_in,
                              void* d_out, int out_size, void* d_ws, size_t ws_size,
                              hipStream_t stream) {
    const float* predict = (const float*)d_in[0];  // [8,1,96,96] f32
    const float* target  = (const float*)d_in[1];  // [8,1,96,96] f32
    float* out = (float*)d_out;                    // scalar f32
    float* ws  = (float*)d_ws;                     // 128 partial maxes

    haus_partial<<<dim3(8 * 2 * NSLICE), dim3(BLK), 0, stream>>>(predict, target, ws);
    haus_final<<<dim3(1), dim3(128), 0, stream>>>(ws, out);
}